// Round 8
// baseline (47.478 us; speedup 1.0000x reference)
//
#include <hip/hip_runtime.h>

// DependencyGenerator, R8: single fused kernel.
// Grid = rows(128) x stripes(16). Each block fills an INTERLEAVED stripe of
// its row (same global store pattern as the R5 grid-stride fill), so scatter
// targets with (idx>>10)&15 == stripe belong exclusively to this block ->
// no inter-block ordering. After __syncthreads (drains own fill stores),
// lane 0 replays the row's 511 entries IN ORDER for its stripe: sequential
// stores give numpy last-duplicate-wins semantics with no O(n^2) scan.

#define SEQ_L   512
#define LM1     511                 // scatter entries per row
#define ROWF4   65536               // float4 elements per row (262144 floats)
#define SPB     16                  // stripe-blocks per row
#define NT      256
#define ITERS   (ROWF4 / (SPB * NT))  // 16 float4 stores per thread

typedef float vfloat4 __attribute__((ext_vector_type(4)));

__global__ __launch_bounds__(NT) void depmask_fused(
    const int*   __restrict__ dep_i,
    const int*   __restrict__ dep_j,
    const int*   __restrict__ dep_type,
    const float* __restrict__ dep_emb,
    float*       __restrict__ out)
{
    __shared__ int   s_idx[LM1];
    __shared__ float s_val[LM1];

    const int row = blockIdx.x / SPB;
    const int s   = blockIdx.x % SPB;
    const int t   = threadIdx.x;

    // Stage the row's entries (coalesced; 16x redundant across stripes but
    // L2-cached, ~1.5 KB/row).
    const int base = row * LM1;
    for (int k = t; k < LM1; k += NT) {
        s_idx[k] = dep_i[base + k] * SEQ_L + dep_j[base + k];
        s_val[k] = dep_emb[dep_type[base + k]];   // 53-entry table, L1-resident
    }

    // Fill this block's interleaved stripe: iteration `it` writes the
    // contiguous 16 KB window [it*16384 floats), block s owns floats
    // [s*1024, s*1024+1024) of each window.
    vfloat4* o4 = reinterpret_cast<vfloat4*>(out) + (size_t)row * ROWF4;
    const vfloat4 ones = {1.f, 1.f, 1.f, 1.f};
    #pragma unroll
    for (int it = 0; it < ITERS; ++it)
        o4[it * (SPB * NT) + s * NT + t] = ones;

    // Drain this block's fill stores; stripe addresses are private to this
    // block, so no cross-block ordering is required.
    __syncthreads();

    // Sequential replay on lane 0: last duplicate wins by construction.
    if (t == 0) {
        float* rowout = out + (size_t)row * (ROWF4 * 4);
        for (int k = 0; k < LM1; ++k) {
            const int idx = s_idx[k];
            if (((idx >> 10) & (SPB - 1)) == s)
                rowout[idx] = s_val[k];
        }
    }
}

extern "C" void kernel_launch(void* const* d_in, const int* in_sizes, int n_in,
                              void* d_out, int out_size, void* d_ws, size_t ws_size,
                              hipStream_t stream) {
    const int*   dep_i    = (const int*)  d_in[0];
    const int*   dep_j    = (const int*)  d_in[1];
    const int*   dep_type = (const int*)  d_in[2];
    // d_in[3] = seq_len scalar (512) -- compile-time constant here
    const float* dep_emb  = (const float*)d_in[4];
    float*       out      = (float*)      d_out;

    const int b = in_sizes[0] / LM1;   // 128
    depmask_fused<<<dim3(b * SPB), dim3(NT), 0, stream>>>(
        dep_i, dep_j, dep_type, dep_emb, out);
}